// Round 11
// baseline (256.083 us; speedup 1.0000x reference)
//
#include <hip/hip_runtime.h>
#include <hip/hip_bf16.h>
#include <cstdint>

// B=2, T=2048, C=1024, H=16, HD=64, M=256, S=2560. fp32 inputs (proven R3-R6).

typedef __bf16 bf16x8_t __attribute__((ext_vector_type(8)));
typedef __bf16 bf16x4_t __attribute__((ext_vector_type(4)));
typedef float f32x4_t __attribute__((ext_vector_type(4)));

__device__ __forceinline__ f32x4_t mfma16(bf16x8_t a, bf16x8_t b, f32x4_t c) {
    return __builtin_amdgcn_mfma_f32_16x16x32_bf16(a, b, c, 0, 0, 0);
}

__device__ __forceinline__ void gl2lds16(const void* g, void* l) {
    __builtin_amdgcn_global_load_lds(
        (__attribute__((address_space(1))) uint32_t*)(uintptr_t)g,
        (__attribute__((address_space(3))) uint32_t*)l, 16, 0, 0);
}

// arena element offsets (bf16), in setup_inputs order; total 9458704
#define OFF_X   0
#define OFF_FWD 4194304
#define OFF_REV 4718592
#define OFF_WQ  5242880
#define OFF_WK  6291456
#define OFF_WV  7340032
#define OFF_WO  8388608
#define OFF_GW  9437184
#define OFF_GB  9453568
#define OFF_CW  9453584
#define OFF_CB  9457680
#define N_TOT   9458704

// ---------------------------------------------------------------------------
// Fused convert: all 11 fp32 inputs -> one contiguous bf16 arena.
// ---------------------------------------------------------------------------
__global__ __launch_bounds__(256) void conv_all_kernel(
    const void* p0, const void* p1, const void* p2, const void* p3,
    const void* p4, const void* p5, const void* p6, const void* p7,
    const void* p8, const void* p9, const void* p10,
    __hip_bfloat16* __restrict__ arena)
{
    const int i = (blockIdx.x * 256 + threadIdx.x) * 4;
    if (i >= N_TOT) return;
    const void* src; int off;
    if      (i < OFF_FWD) { src = p0;  off = OFF_X;   }
    else if (i < OFF_REV) { src = p1;  off = OFF_FWD; }
    else if (i < OFF_WQ)  { src = p2;  off = OFF_REV; }
    else if (i < OFF_WK)  { src = p3;  off = OFF_WQ;  }
    else if (i < OFF_WV)  { src = p4;  off = OFF_WK;  }
    else if (i < OFF_WO)  { src = p5;  off = OFF_WV;  }
    else if (i < OFF_GW)  { src = p6;  off = OFF_WO;  }
    else if (i < OFF_GB)  { src = p7;  off = OFF_GW;  }
    else if (i < OFF_CW)  { src = p8;  off = OFF_GB;  }
    else if (i < OFF_CB)  { src = p9;  off = OFF_CW;  }
    else                  { src = p10; off = OFF_CB;  }
    const int j = i - off;
    const float4 f = *(const float4*)((const float*)src + j);
    arena[i + 0] = __float2bfloat16(f.x);
    arena[i + 1] = __float2bfloat16(f.y);
    arena[i + 2] = __float2bfloat16(f.z);
    arena[i + 3] = __float2bfloat16(f.w);
}

// ---------------------------------------------------------------------------
// GEMM core: 128x128 tile, BK=32, double-buffered LDS (R9 structure).
// ---------------------------------------------------------------------------
__device__ __forceinline__ void gemm_core(
    const __hip_bfloat16* __restrict__ A, const __hip_bfloat16* __restrict__ B,
    void* __restrict__ C, int ldc, int f32o, int arow0, int brow0,
    __hip_bfloat16* As, __hip_bfloat16* Bs)   // each 2*128*32 elems
{
    const int tid  = threadIdx.x;
    const int lane = tid & 63;
    const int wid  = tid >> 6;
    const int q4   = lane >> 4;
    const int c16  = lane & 15;
    const int wm   = (wid >> 1) * 64;
    const int wn   = (wid & 1) * 64;
    const int c0 = tid;
    const int c1 = tid + 256;
    const __hip_bfloat16* gA0 = A + (size_t)(arow0 + (c0 >> 2)) * 1024 + ((c0 & 3) << 3);
    const __hip_bfloat16* gA1 = A + (size_t)(arow0 + (c1 >> 2)) * 1024 + ((c1 & 3) << 3);
    const __hip_bfloat16* gB0 = B + (size_t)(brow0 + (c0 >> 2)) * 1024 + ((c0 & 3) << 3);
    const __hip_bfloat16* gB1 = B + (size_t)(brow0 + (c1 >> 2)) * 1024 + ((c1 & 3) << 3);

    f32x4_t acc[4][4];
#pragma unroll
    for (int i = 0; i < 4; ++i)
#pragma unroll
        for (int j = 0; j < 4; ++j)
#pragma unroll
            for (int r = 0; r < 4; ++r) acc[i][j][r] = 0.0f;

    gl2lds16(gA0, As + c0 * 8);
    gl2lds16(gA1, As + c1 * 8);
    gl2lds16(gB0, Bs + c0 * 8);
    gl2lds16(gB1, Bs + c1 * 8);

    for (int it = 0; it < 32; ++it) {
        __hip_bfloat16* curA = As + (it & 1) * 4096;
        __hip_bfloat16* curB = Bs + (it & 1) * 4096;
        __syncthreads();
        if (it < 31) {
            const int nk = (it + 1) * 32;
            __hip_bfloat16* nA = As + ((it + 1) & 1) * 4096;
            __hip_bfloat16* nB = Bs + ((it + 1) & 1) * 4096;
            gl2lds16(gA0 + nk, nA + c0 * 8);
            gl2lds16(gA1 + nk, nA + c1 * 8);
            gl2lds16(gB0 + nk, nB + c0 * 8);
            gl2lds16(gB1 + nk, nB + c1 * 8);
        }
        bf16x8_t af[4], bfr[4];
#pragma unroll
        for (int i = 0; i < 4; ++i)
            af[i] = *(const bf16x8_t*)&curA[(wm + i * 16 + c16) * 32 + q4 * 8];
#pragma unroll
        for (int j = 0; j < 4; ++j)
            bfr[j] = *(const bf16x8_t*)&curB[(wn + j * 16 + c16) * 32 + q4 * 8];
#pragma unroll
        for (int i = 0; i < 4; ++i)
#pragma unroll
            for (int j = 0; j < 4; ++j)
                acc[i][j] = mfma16(af[i], bfr[j], acc[i][j]);
    }
#pragma unroll
    for (int i = 0; i < 4; ++i) {
        const int mg = arow0 + wm + i * 16 + q4 * 4;
#pragma unroll
        for (int j = 0; j < 4; ++j) {
            const int ng = brow0 + wn + j * 16 + c16;
#pragma unroll
            for (int r = 0; r < 4; ++r) {
                const size_t idx = (size_t)(mg + r) * ldc + ng;
                if (f32o) ((float*)C)[idx] = acc[i][j][r];
                else ((__hip_bfloat16*)C)[idx] = __float2bfloat16(acc[i][j][r]);
            }
        }
    }
}

// Fused QK + V^T launch: 960 uniform-cost blocks.
__global__ __launch_bounds__(256) void qkv_kernel(
    const __hip_bfloat16* __restrict__ x, const __hip_bfloat16* __restrict__ Wqk,
    const __hip_bfloat16* __restrict__ Wv,
    __hip_bfloat16* __restrict__ QK, __hip_bfloat16* __restrict__ Vt)
{
    __shared__ __align__(16) __hip_bfloat16 As[2 * 128 * 32];
    __shared__ __align__(16) __hip_bfloat16 Bs[2 * 128 * 32];
    int id = blockIdx.x;
    if (id < 640)
        gemm_core(x, Wqk, QK, 2048, 0, (id >> 4) * 128, (id & 15) * 128, As, Bs);
    else {
        id -= 640;
        gemm_core(Wv, x, Vt, 5120, 0, (id & 7) * 128, (id >> 3) * 128, As, Bs);
    }
}

__global__ __launch_bounds__(256) void gemm_bt_kernel(
    const __hip_bfloat16* __restrict__ A, const __hip_bfloat16* __restrict__ B,
    void* __restrict__ C, int ldc, int f32o)
{
    __shared__ __align__(16) __hip_bfloat16 As[2 * 128 * 32];
    __shared__ __align__(16) __hip_bfloat16 Bs[2 * 128 * 32];
    gemm_core(A, B, C, ldc, f32o, blockIdx.x * 128, blockIdx.y * 128, As, Bs);
}

// ---------------------------------------------------------------------------
// Gate via MFMA (Q from fused QK buffer, ld 2048)
// ---------------------------------------------------------------------------
__global__ __launch_bounds__(64) void gate_kernel(
    const __hip_bfloat16* __restrict__ QK, const __hip_bfloat16* __restrict__ gw,
    const __hip_bfloat16* __restrict__ gb, float* __restrict__ G)
{
    const int base = blockIdx.x * 16;
    const int lane = threadIdx.x;
    const int q4   = lane >> 4;
    const int c16  = lane & 15;
    f32x4_t acc = {0.0f, 0.0f, 0.0f, 0.0f};
    const __hip_bfloat16* qrow = QK + (size_t)(base + c16) * 2048 + q4 * 8;
    const __hip_bfloat16* wrow = gw + (size_t)c16 * 1024 + q4 * 8;
#pragma unroll
    for (int kk = 0; kk < 32; ++kk) {
        const bf16x8_t a = *(const bf16x8_t*)(qrow + kk * 32);
        const bf16x8_t w = *(const bf16x8_t*)(wrow + kk * 32);
        acc = mfma16(a, w, acc);
    }
    const float bias = __bfloat162float(gb[c16]);
#pragma unroll
    for (int r = 0; r < 4; ++r) {
        const int row = base + q4 * 4 + r;
        G[(size_t)row * 16 + c16] = 1.0f / (1.0f + __expf(-(acc[r] + bias)));
    }
}

// ---------------------------------------------------------------------------
// Flash attention v4: R9's proven S-orientation and P path (scalar b16
// P-writes, PSTR=72 — measured cheap), but 32 q-rows per wave via 2-wave
// 128-thread blocks (halves K/V fragment reads per unit work). Grid 1024,
// LDS 25.6 KB (6 blocks/CU ceiling).
// ---------------------------------------------------------------------------
#define PSTR 72
__global__ __launch_bounds__(128) void attn_kernel(
    const __hip_bfloat16* __restrict__ QK,
    const __hip_bfloat16* __restrict__ Vt,
    const float* __restrict__ G, __hip_bfloat16* __restrict__ Y)
{
    __shared__ __align__(16) __hip_bfloat16 Ks[64 * 64];
    __shared__ __align__(16) __hip_bfloat16 Vs[64 * 64];
    __shared__ __align__(16) __hip_bfloat16 Pq[2][32 * PSTR];  // [wave][q][key]
    const int flat = blockIdx.x;          // 0..1023
    const int bh   = flat & 31;           // pin bh's K/V to one XCD
    const int tIdx = 31 - (flat >> 5);    // long blocks first
    const int b    = bh >> 4;
    const int h    = bh & 15;
    const int tid  = threadIdx.x;         // 0..127
    const int wid  = tid >> 6;            // 0..1
    const int lane = tid & 63;
    const int q4   = lane >> 4;
    const int c16  = lane & 15;
    const int rowbase = tIdx * 64 + wid * 32;  // wave's 32 q-rows

    // Q A-fragments for 2 m-groups: rows rowbase + mg*16 + c16
    bf16x8_t qa[2][2];
    float rs[2][4], gate[2][4];
    f32x4_t acc[4][2];
#pragma unroll
    for (int mg = 0; mg < 2; ++mg) {
        const __hip_bfloat16* qrow =
            QK + (size_t)(b * 2048 + rowbase + mg * 16 + c16) * 2048 + h * 64;
        qa[mg][0] = *(const bf16x8_t*)(qrow + q4 * 8);
        qa[mg][1] = *(const bf16x8_t*)(qrow + 32 + q4 * 8);
#pragma unroll
        for (int r = 0; r < 4; ++r) {
            rs[mg][r] = 0.0f;
            gate[mg][r] =
                G[(size_t)(b * 2048 + rowbase + mg * 16 + q4 * 4 + r) * 16 + h];
        }
    }
#pragma unroll
    for (int fp = 0; fp < 4; ++fp)
#pragma unroll
        for (int mg = 0; mg < 2; ++mg)
#pragma unroll
            for (int r = 0; r < 4; ++r) acc[fp][mg][r] = 0.0f;

    const int nCausal = tIdx + 1;
    const int nTiles  = nCausal + 8;
    auto kvRow = [&](int tile) -> int {
        if (tile < nCausal) return b * 2048 + tile * 64;
        const int mi = (tile - nCausal) * 64;
        return (mi < 256) ? 4096 + b * 256 + mi : 4608 + b * 256 + (mi - 256);
    };

    // staging: 4 slots per thread per matrix; s = i*128 + tid
    int srow[4], sch[4];
#pragma unroll
    for (int i = 0; i < 4; ++i) {
        const int s = i * 128 + tid;
        srow[i] = s >> 3;
        sch[i]  = (s & 7) ^ (srow[i] & 7);
    }
    const int sw0 = (q4 ^ (c16 & 7)) * 8;
    const int sw1 = ((q4 + 4) ^ (c16 & 7)) * 8;
    const __hip_bfloat16* Kbase = QK + 1024 + h * 64;  // K cols of fused buffer

    for (int tile = 0; tile < nTiles; ++tile) {
        const bool isMem  = (tile >= nCausal);
        const bool isDiag = (tile == nCausal - 1);
        const int  vr     = kvRow(tile);
        __syncthreads();
#pragma unroll
        for (int i = 0; i < 4; ++i) {
            gl2lds16(Kbase + (size_t)(vr + srow[i]) * 2048 + sch[i] * 8,
                     &Ks[(i * 128 + tid) * 8]);
            gl2lds16(Vt + (size_t)(h * 64 + srow[i]) * 5120 + vr + sch[i] * 8,
                     &Vs[(i * 128 + tid) * 8]);
        }
        __syncthreads();
        bf16x8_t kb0[4], kb1[4], vb0[4], vb1[4];
#pragma unroll
        for (int f = 0; f < 4; ++f) {
            kb0[f] = *(const bf16x8_t*)&Ks[(f * 16 + c16) * 64 + sw0];
            kb1[f] = *(const bf16x8_t*)&Ks[(f * 16 + c16) * 64 + sw1];
            vb0[f] = *(const bf16x8_t*)&Vs[(f * 16 + c16) * 64 + sw0];
            vb1[f] = *(const bf16x8_t*)&Vs[(f * 16 + c16) * 64 + sw1];
        }
        // S = Q @ K^T per m-group; C-layout row = mg*16+q4*4+r, col = f*16+c16
#pragma unroll
        for (int f = 0; f < 4; ++f)
#pragma unroll
            for (int mg = 0; mg < 2; ++mg) {
                f32x4_t z = {0.0f, 0.0f, 0.0f, 0.0f};
                z = mfma16(qa[mg][0], kb0[f], z);
                z = mfma16(qa[mg][1], kb1[f], z);
#pragma unroll
                for (int r = 0; r < 4; ++r) {
                    float p = __expf(z[r] * 0.125f);
                    if (isDiag) {
                        const int kg = tile * 64 + f * 16 + c16;
                        if (kg > rowbase + mg * 16 + q4 * 4 + r) p = 0.0f;
                    }
                    rs[mg][r] += p;                // ungated denominator
                    if (isMem) p *= gate[mg][r];   // gate mem contribution only
                    Pq[wid][(mg * 16 + q4 * 4 + r) * PSTR + f * 16 + c16] =
                        __float2bfloat16(p);
                }
            }
        // P A-fragments (rows mg*16 + c16)
        bf16x8_t pa[2][2];
#pragma unroll
        for (int mg = 0; mg < 2; ++mg) {
            pa[mg][0] = *(const bf16x8_t*)&Pq[wid][(mg * 16 + c16) * PSTR + q4 * 8];
            pa[mg][1] = *(const bf16x8_t*)&Pq[wid][(mg * 16 + c16) * PSTR + 32 + q4 * 8];
        }
        // PV: acc[fp][mg] += P @ V
#pragma unroll
        for (int fp = 0; fp < 4; ++fp)
#pragma unroll
            for (int mg = 0; mg < 2; ++mg) {
                acc[fp][mg] = mfma16(pa[mg][0], vb0[fp], acc[fp][mg]);
                acc[fp][mg] = mfma16(pa[mg][1], vb1[fp], acc[fp][mg]);
            }
    }
    // epilogue: reduce l over 16-lane quad-groups, then store
#pragma unroll
    for (int m = 1; m <= 8; m <<= 1)
#pragma unroll
        for (int mg = 0; mg < 2; ++mg)
#pragma unroll
            for (int r = 0; r < 4; ++r)
                rs[mg][r] += __shfl_xor(rs[mg][r], m, 64);
    float inv[2][4];
#pragma unroll
    for (int mg = 0; mg < 2; ++mg)
#pragma unroll
        for (int r = 0; r < 4; ++r) inv[mg][r] = 1.0f / rs[mg][r];
#pragma unroll
    for (int fp = 0; fp < 4; ++fp)
#pragma unroll
        for (int mg = 0; mg < 2; ++mg)
#pragma unroll
            for (int r = 0; r < 4; ++r) {
                const int tg = rowbase + mg * 16 + q4 * 4 + r;
                Y[(size_t)(b * 2048 + tg) * 1024 + h * 64 + fp * 16 + c16] =
                    __float2bfloat16(acc[fp][mg][r] * inv[mg][r]);
            }
}

// ---------------------------------------------------------------------------
// Canon depthwise causal conv (K=4) + bias, 4 channels/thread
// ---------------------------------------------------------------------------
__global__ __launch_bounds__(256) void canon_kernel(
    const __hip_bfloat16* __restrict__ Yin, const __hip_bfloat16* __restrict__ cw,
    const __hip_bfloat16* __restrict__ cb, __hip_bfloat16* __restrict__ Yout)
{
    const int idx = (blockIdx.x * 256 + threadIdx.x) * 4;
    const int c = idx & 1023;
    const int t = (idx >> 10) & 2047;
    const bf16x4_t y0 = *(const bf16x4_t*)(Yin + idx);
    const bf16x4_t bb = *(const bf16x4_t*)(cb + c);
    float a[4];
#pragma unroll
    for (int i = 0; i < 4; ++i) a[i] = (float)y0[i] + (float)bb[i];
    const bf16x8_t w01 = *(const bf16x8_t*)(cw + c * 4);
    const bf16x8_t w23 = *(const bf16x8_t*)(cw + c * 4 + 8);
#pragma unroll
    for (int j = 0; j < 4; ++j) {
        if (t - 3 + j >= 0) {
            const bf16x4_t yj = *(const bf16x4_t*)(Yin + idx + (j - 3) * 1024);
            a[0] += (float)yj[0] * (float)w01[j];
            a[1] += (float)yj[1] * (float)w01[4 + j];
            a[2] += (float)yj[2] * (float)w23[j];
            a[3] += (float)yj[3] * (float)w23[4 + j];
        }
    }
    bf16x4_t o;
#pragma unroll
    for (int i = 0; i < 4; ++i) o[i] = (__bf16)a[i];
    *(bf16x4_t*)(Yout + idx) = o;
}

// ---------------------------------------------------------------------------
extern "C" void kernel_launch(void* const* d_in, const int* in_sizes, int n_in,
                              void* d_out, int out_size, void* d_ws, size_t ws_size,
                              hipStream_t stream)
{
    char* ws = (char*)d_ws;
    const size_t MB = 1ull << 20;
    if (ws_size < 50 * MB) return;  // canary

    __hip_bfloat16* arena = (__hip_bfloat16*)ws;              // 18.05 MB
    __hip_bfloat16* QK    = (__hip_bfloat16*)(ws + 19 * MB);  // 20 MB (5120x2048)
    __hip_bfloat16* Vt    = (__hip_bfloat16*)(ws + 39 * MB);  // 10 MB (1024x5120)
    float*          G     = (float*)(ws + 49 * MB);           // 256 KB
    __hip_bfloat16* Y1    = (__hip_bfloat16*)ws;              // reuse x region
    __hip_bfloat16* Y2    = QK;                               // reuse after attention

    const dim3 blk(256);
    conv_all_kernel<<<dim3((N_TOT / 4 + 255) / 256), blk, 0, stream>>>(
        d_in[0], d_in[1], d_in[2], d_in[3], d_in[4], d_in[5], d_in[6],
        d_in[7], d_in[8], d_in[9], d_in[10], arena);

    const __hip_bfloat16* xB  = arena + OFF_X;
    const __hip_bfloat16* WqB = arena + OFF_WQ;  // [Wq;Wk] contiguous
    const __hip_bfloat16* WvB = arena + OFF_WV;
    const __hip_bfloat16* WoB = arena + OFF_WO;

    qkv_kernel<<<dim3(960), blk, 0, stream>>>(xB, WqB, WvB, QK, Vt);
    gate_kernel<<<dim3(256), dim3(64), 0, stream>>>(QK, arena + OFF_GW, arena + OFF_GB, G);
    attn_kernel<<<dim3(1024), dim3(128), 0, stream>>>(QK, Vt, G, Y1);
    canon_kernel<<<dim3(4096), blk, 0, stream>>>(Y1, arena + OFF_CW, arena + OFF_CB, Y2);
    gemm_bt_kernel<<<dim3(32, 8), blk, 0, stream>>>(Y2, WoB, d_out, 1024, 1);
}

// Round 12
// 241.411 us; speedup vs baseline: 1.0608x; 1.0608x over previous
//
#include <hip/hip_runtime.h>
#include <hip/hip_bf16.h>
#include <cstdint>

// B=2, T=2048, C=1024, H=16, HD=64, M=256, S=2560. fp32 inputs (proven R3-R6).

typedef __bf16 bf16x8_t __attribute__((ext_vector_type(8)));
typedef __bf16 bf16x4_t __attribute__((ext_vector_type(4)));
typedef float f32x4_t __attribute__((ext_vector_type(4)));

__device__ __forceinline__ f32x4_t mfma16(bf16x8_t a, bf16x8_t b, f32x4_t c) {
    return __builtin_amdgcn_mfma_f32_16x16x32_bf16(a, b, c, 0, 0, 0);
}

__device__ __forceinline__ void gl2lds16(const void* g, void* l) {
    __builtin_amdgcn_global_load_lds(
        (__attribute__((address_space(1))) uint32_t*)(uintptr_t)g,
        (__attribute__((address_space(3))) uint32_t*)l, 16, 0, 0);
}

// arena element offsets (bf16), in setup_inputs order; total 9458704
#define OFF_X   0
#define OFF_FWD 4194304
#define OFF_REV 4718592
#define OFF_WQ  5242880
#define OFF_WK  6291456
#define OFF_WV  7340032
#define OFF_WO  8388608
#define OFF_GW  9437184
#define OFF_GB  9453568
#define OFF_CW  9453584
#define OFF_CB  9457680
#define N_TOT   9458704

// ---------------------------------------------------------------------------
// Fused convert: all 11 fp32 inputs -> one contiguous bf16 arena.
// ---------------------------------------------------------------------------
__global__ __launch_bounds__(256) void conv_all_kernel(
    const void* p0, const void* p1, const void* p2, const void* p3,
    const void* p4, const void* p5, const void* p6, const void* p7,
    const void* p8, const void* p9, const void* p10,
    __hip_bfloat16* __restrict__ arena)
{
    const int i = (blockIdx.x * 256 + threadIdx.x) * 4;
    if (i >= N_TOT) return;
    const void* src; int off;
    if      (i < OFF_FWD) { src = p0;  off = OFF_X;   }
    else if (i < OFF_REV) { src = p1;  off = OFF_FWD; }
    else if (i < OFF_WQ)  { src = p2;  off = OFF_REV; }
    else if (i < OFF_WK)  { src = p3;  off = OFF_WQ;  }
    else if (i < OFF_WV)  { src = p4;  off = OFF_WK;  }
    else if (i < OFF_WO)  { src = p5;  off = OFF_WV;  }
    else if (i < OFF_GW)  { src = p6;  off = OFF_WO;  }
    else if (i < OFF_GB)  { src = p7;  off = OFF_GW;  }
    else if (i < OFF_CW)  { src = p8;  off = OFF_GB;  }
    else if (i < OFF_CB)  { src = p9;  off = OFF_CW;  }
    else                  { src = p10; off = OFF_CB;  }
    const int j = i - off;
    const float4 f = *(const float4*)((const float*)src + j);
    arena[i + 0] = __float2bfloat16(f.x);
    arena[i + 1] = __float2bfloat16(f.y);
    arena[i + 2] = __float2bfloat16(f.z);
    arena[i + 3] = __float2bfloat16(f.w);
}

// ---------------------------------------------------------------------------
// GEMM core: 128x128 tile, BK=32, double-buffered LDS (R9 structure).
// ---------------------------------------------------------------------------
__device__ __forceinline__ void gemm_core(
    const __hip_bfloat16* __restrict__ A, const __hip_bfloat16* __restrict__ B,
    void* __restrict__ C, int ldc, int f32o, int arow0, int brow0,
    __hip_bfloat16* As, __hip_bfloat16* Bs)   // each 2*128*32 elems
{
    const int tid  = threadIdx.x;
    const int lane = tid & 63;
    const int wid  = tid >> 6;
    const int q4   = lane >> 4;
    const int c16  = lane & 15;
    const int wm   = (wid >> 1) * 64;
    const int wn   = (wid & 1) * 64;
    const int c0 = tid;
    const int c1 = tid + 256;
    const __hip_bfloat16* gA0 = A + (size_t)(arow0 + (c0 >> 2)) * 1024 + ((c0 & 3) << 3);
    const __hip_bfloat16* gA1 = A + (size_t)(arow0 + (c1 >> 2)) * 1024 + ((c1 & 3) << 3);
    const __hip_bfloat16* gB0 = B + (size_t)(brow0 + (c0 >> 2)) * 1024 + ((c0 & 3) << 3);
    const __hip_bfloat16* gB1 = B + (size_t)(brow0 + (c1 >> 2)) * 1024 + ((c1 & 3) << 3);

    f32x4_t acc[4][4];
#pragma unroll
    for (int i = 0; i < 4; ++i)
#pragma unroll
        for (int j = 0; j < 4; ++j)
#pragma unroll
            for (int r = 0; r < 4; ++r) acc[i][j][r] = 0.0f;

    gl2lds16(gA0, As + c0 * 8);
    gl2lds16(gA1, As + c1 * 8);
    gl2lds16(gB0, Bs + c0 * 8);
    gl2lds16(gB1, Bs + c1 * 8);

    for (int it = 0; it < 32; ++it) {
        __hip_bfloat16* curA = As + (it & 1) * 4096;
        __hip_bfloat16* curB = Bs + (it & 1) * 4096;
        __syncthreads();
        if (it < 31) {
            const int nk = (it + 1) * 32;
            __hip_bfloat16* nA = As + ((it + 1) & 1) * 4096;
            __hip_bfloat16* nB = Bs + ((it + 1) & 1) * 4096;
            gl2lds16(gA0 + nk, nA + c0 * 8);
            gl2lds16(gA1 + nk, nA + c1 * 8);
            gl2lds16(gB0 + nk, nB + c0 * 8);
            gl2lds16(gB1 + nk, nB + c1 * 8);
        }
        bf16x8_t af[4], bfr[4];
#pragma unroll
        for (int i = 0; i < 4; ++i)
            af[i] = *(const bf16x8_t*)&curA[(wm + i * 16 + c16) * 32 + q4 * 8];
#pragma unroll
        for (int j = 0; j < 4; ++j)
            bfr[j] = *(const bf16x8_t*)&curB[(wn + j * 16 + c16) * 32 + q4 * 8];
#pragma unroll
        for (int i = 0; i < 4; ++i)
#pragma unroll
            for (int j = 0; j < 4; ++j)
                acc[i][j] = mfma16(af[i], bfr[j], acc[i][j]);
    }
#pragma unroll
    for (int i = 0; i < 4; ++i) {
        const int mg = arow0 + wm + i * 16 + q4 * 4;
#pragma unroll
        for (int j = 0; j < 4; ++j) {
            const int ng = brow0 + wn + j * 16 + c16;
#pragma unroll
            for (int r = 0; r < 4; ++r) {
                const size_t idx = (size_t)(mg + r) * ldc + ng;
                if (f32o) ((float*)C)[idx] = acc[i][j][r];
                else ((__hip_bfloat16*)C)[idx] = __float2bfloat16(acc[i][j][r]);
            }
        }
    }
}

// Fused QK + V^T launch: 960 uniform-cost blocks.
__global__ __launch_bounds__(256) void qkv_kernel(
    const __hip_bfloat16* __restrict__ x, const __hip_bfloat16* __restrict__ Wqk,
    const __hip_bfloat16* __restrict__ Wv,
    __hip_bfloat16* __restrict__ QK, __hip_bfloat16* __restrict__ Vt)
{
    __shared__ __align__(16) __hip_bfloat16 As[2 * 128 * 32];
    __shared__ __align__(16) __hip_bfloat16 Bs[2 * 128 * 32];
    int id = blockIdx.x;
    if (id < 640)
        gemm_core(x, Wqk, QK, 2048, 0, (id >> 4) * 128, (id & 15) * 128, As, Bs);
    else {
        id -= 640;
        gemm_core(Wv, x, Vt, 5120, 0, (id & 7) * 128, (id >> 3) * 128, As, Bs);
    }
}

__global__ __launch_bounds__(256) void gemm_bt_kernel(
    const __hip_bfloat16* __restrict__ A, const __hip_bfloat16* __restrict__ B,
    void* __restrict__ C, int ldc, int f32o)
{
    __shared__ __align__(16) __hip_bfloat16 As[2 * 128 * 32];
    __shared__ __align__(16) __hip_bfloat16 Bs[2 * 128 * 32];
    gemm_core(A, B, C, ldc, f32o, blockIdx.x * 128, blockIdx.y * 128, As, Bs);
}

// ---------------------------------------------------------------------------
// Gate via MFMA (Q from fused QK buffer, ld 2048)
// ---------------------------------------------------------------------------
__global__ __launch_bounds__(64) void gate_kernel(
    const __hip_bfloat16* __restrict__ QK, const __hip_bfloat16* __restrict__ gw,
    const __hip_bfloat16* __restrict__ gb, float* __restrict__ G)
{
    const int base = blockIdx.x * 16;
    const int lane = threadIdx.x;
    const int q4   = lane >> 4;
    const int c16  = lane & 15;
    f32x4_t acc = {0.0f, 0.0f, 0.0f, 0.0f};
    const __hip_bfloat16* qrow = QK + (size_t)(base + c16) * 2048 + q4 * 8;
    const __hip_bfloat16* wrow = gw + (size_t)c16 * 1024 + q4 * 8;
#pragma unroll
    for (int kk = 0; kk < 32; ++kk) {
        const bf16x8_t a = *(const bf16x8_t*)(qrow + kk * 32);
        const bf16x8_t w = *(const bf16x8_t*)(wrow + kk * 32);
        acc = mfma16(a, w, acc);
    }
    const float bias = __bfloat162float(gb[c16]);
#pragma unroll
    for (int r = 0; r < 4; ++r) {
        const int row = base + q4 * 4 + r;
        G[(size_t)row * 16 + c16] = 1.0f / (1.0f + __expf(-(acc[r] + bias)));
    }
}

// ---------------------------------------------------------------------------
// Flash attention v5 = R9 shape (4 waves x 16q, grid 1024) + DOUBLE-BUFFERED
// K/V staging with ONE barrier per tile: stage(t+1) issues right after the
// barrier, ahead of tile t's fragment reads + compute, so the vmcnt drain
// overlaps a full tile of work (the R9-GEMM dbuf pattern applied to attn).
// ---------------------------------------------------------------------------
#define PSTR 72
__global__ __launch_bounds__(256) void attn_kernel(
    const __hip_bfloat16* __restrict__ QK,
    const __hip_bfloat16* __restrict__ Vt,
    const float* __restrict__ G, __hip_bfloat16* __restrict__ Y)
{
    __shared__ __align__(16) __hip_bfloat16 Ks[2][64 * 64];
    __shared__ __align__(16) __hip_bfloat16 Vs[2][64 * 64];
    __shared__ __align__(16) __hip_bfloat16 Plds[4][16 * PSTR];
    const int flat = blockIdx.x;          // 0..1023
    const int bh   = flat & 31;           // pin bh's K/V to one XCD
    const int tIdx = 31 - (flat >> 5);    // long blocks first
    const int b    = bh >> 4;
    const int h    = bh & 15;
    const int tid  = threadIdx.x;
    const int wid  = tid >> 6;
    const int lane = tid & 63;
    const int q4   = lane >> 4;
    const int c16  = lane & 15;
    const int rowbase = tIdx * 64 + wid * 16;

    const __hip_bfloat16* qrow = QK + (size_t)(b * 2048 + rowbase + c16) * 2048 + h * 64;
    const bf16x8_t qa0 = *(const bf16x8_t*)(qrow + q4 * 8);
    const bf16x8_t qa1 = *(const bf16x8_t*)(qrow + 32 + q4 * 8);

    float rs[4], gate[4];
    f32x4_t acc[4];
#pragma unroll
    for (int fp = 0; fp < 4; ++fp)
#pragma unroll
        for (int r = 0; r < 4; ++r) acc[fp][r] = 0.0f;
#pragma unroll
    for (int r = 0; r < 4; ++r) {
        rs[r] = 0.0f;
        gate[r] = G[(size_t)(b * 2048 + rowbase + q4 * 4 + r) * 16 + h];
    }

    const int nCausal = tIdx + 1;
    const int nTiles  = nCausal + 8;
    auto kvRow = [&](int tile) -> int {
        if (tile < nCausal) return b * 2048 + tile * 64;
        const int mi = (tile - nCausal) * 64;
        return (mi < 256) ? 4096 + b * 256 + mi : 4608 + b * 256 + (mi - 256);
    };

    const int srow0 = tid >> 3,         sch0 = (tid & 7) ^ (srow0 & 7);
    const int srow1 = (tid + 256) >> 3, sch1 = (tid & 7) ^ (srow1 & 7);
    const int sw0 = (q4 ^ (c16 & 7)) * 8;
    const int sw1 = ((q4 + 4) ^ (c16 & 7)) * 8;
    const __hip_bfloat16* Kbase = QK + 1024 + h * 64;  // K cols of fused buffer

    auto stage = [&](int tile, int buf) {
        const int vr = kvRow(tile);
        gl2lds16(Kbase + (size_t)(vr + srow0) * 2048 + sch0 * 8, &Ks[buf][tid * 8]);
        gl2lds16(Kbase + (size_t)(vr + srow1) * 2048 + sch1 * 8, &Ks[buf][(tid + 256) * 8]);
        gl2lds16(Vt + (size_t)(h * 64 + srow0) * 5120 + vr + sch0 * 8, &Vs[buf][tid * 8]);
        gl2lds16(Vt + (size_t)(h * 64 + srow1) * 5120 + vr + sch1 * 8, &Vs[buf][(tid + 256) * 8]);
    };
    stage(0, 0);   // prologue

    for (int tile = 0; tile < nTiles; ++tile) {
        const int  cur    = tile & 1;
        const bool isMem  = (tile >= nCausal);
        const bool isDiag = (tile == nCausal - 1);
        __syncthreads();                 // stage(tile) complete; old reads done
        if (tile + 1 < nTiles) stage(tile + 1, cur ^ 1);
        bf16x8_t kb0[4], kb1[4], vb0[4], vb1[4];
#pragma unroll
        for (int f = 0; f < 4; ++f) {
            kb0[f] = *(const bf16x8_t*)&Ks[cur][(f * 16 + c16) * 64 + sw0];
            kb1[f] = *(const bf16x8_t*)&Ks[cur][(f * 16 + c16) * 64 + sw1];
            vb0[f] = *(const bf16x8_t*)&Vs[cur][(f * 16 + c16) * 64 + sw0];
            vb1[f] = *(const bf16x8_t*)&Vs[cur][(f * 16 + c16) * 64 + sw1];
        }
        f32x4_t sc[4];
#pragma unroll
        for (int f = 0; f < 4; ++f) {
            f32x4_t z = {0.0f, 0.0f, 0.0f, 0.0f};
            z = mfma16(qa0, kb0[f], z);
            z = mfma16(qa1, kb1[f], z);
            sc[f] = z;
        }
#pragma unroll
        for (int f = 0; f < 4; ++f)
#pragma unroll
            for (int r = 0; r < 4; ++r) {
                float p = __expf(sc[f][r] * 0.125f);
                if (isDiag) {
                    const int sg = tile * 64 + f * 16 + c16;
                    if (sg > rowbase + q4 * 4 + r) p = 0.0f;
                }
                rs[r] += p;                 // ungated denominator
                if (isMem) p *= gate[r];    // gate mem contribution only
                Plds[wid][(q4 * 4 + r) * PSTR + f * 16 + c16] = __float2bfloat16(p);
            }
        const bf16x8_t pa0 = *(const bf16x8_t*)&Plds[wid][c16 * PSTR + q4 * 8];
        const bf16x8_t pa1 = *(const bf16x8_t*)&Plds[wid][c16 * PSTR + 32 + q4 * 8];
#pragma unroll
        for (int fp = 0; fp < 4; ++fp) {
            acc[fp] = mfma16(pa0, vb0[fp], acc[fp]);
            acc[fp] = mfma16(pa1, vb1[fp], acc[fp]);
        }
    }
#pragma unroll
    for (int m = 1; m <= 8; m <<= 1)
#pragma unroll
        for (int r = 0; r < 4; ++r) rs[r] += __shfl_xor(rs[r], m, 64);
    float inv[4];
#pragma unroll
    for (int r = 0; r < 4; ++r) inv[r] = 1.0f / rs[r];
#pragma unroll
    for (int fp = 0; fp < 4; ++fp)
#pragma unroll
        for (int r = 0; r < 4; ++r) {
            const int tg = rowbase + q4 * 4 + r;
            Y[(size_t)(b * 2048 + tg) * 1024 + h * 64 + fp * 16 + c16] =
                __float2bfloat16(acc[fp][r] * inv[r]);
        }
}

// ---------------------------------------------------------------------------
// Canon depthwise causal conv (K=4) + bias, 4 channels/thread
// ---------------------------------------------------------------------------
__global__ __launch_bounds__(256) void canon_kernel(
    const __hip_bfloat16* __restrict__ Yin, const __hip_bfloat16* __restrict__ cw,
    const __hip_bfloat16* __restrict__ cb, __hip_bfloat16* __restrict__ Yout)
{
    const int idx = (blockIdx.x * 256 + threadIdx.x) * 4;
    const int c = idx & 1023;
    const int t = (idx >> 10) & 2047;
    const bf16x4_t y0 = *(const bf16x4_t*)(Yin + idx);
    const bf16x4_t bb = *(const bf16x4_t*)(cb + c);
    float a[4];
#pragma unroll
    for (int i = 0; i < 4; ++i) a[i] = (float)y0[i] + (float)bb[i];
    const bf16x8_t w01 = *(const bf16x8_t*)(cw + c * 4);
    const bf16x8_t w23 = *(const bf16x8_t*)(cw + c * 4 + 8);
#pragma unroll
    for (int j = 0; j < 4; ++j) {
        if (t - 3 + j >= 0) {
            const bf16x4_t yj = *(const bf16x4_t*)(Yin + idx + (j - 3) * 1024);
            a[0] += (float)yj[0] * (float)w01[j];
            a[1] += (float)yj[1] * (float)w01[4 + j];
            a[2] += (float)yj[2] * (float)w23[j];
            a[3] += (float)yj[3] * (float)w23[4 + j];
        }
    }
    bf16x4_t o;
#pragma unroll
    for (int i = 0; i < 4; ++i) o[i] = (__bf16)a[i];
    *(bf16x4_t*)(Yout + idx) = o;
}

// ---------------------------------------------------------------------------
extern "C" void kernel_launch(void* const* d_in, const int* in_sizes, int n_in,
                              void* d_out, int out_size, void* d_ws, size_t ws_size,
                              hipStream_t stream)
{
    char* ws = (char*)d_ws;
    const size_t MB = 1ull << 20;
    if (ws_size < 50 * MB) return;  // canary

    __hip_bfloat16* arena = (__hip_bfloat16*)ws;              // 18.05 MB
    __hip_bfloat16* QK    = (__hip_bfloat16*)(ws + 19 * MB);  // 20 MB (5120x2048)
    __hip_bfloat16* Vt    = (__hip_bfloat16*)(ws + 39 * MB);  // 10 MB (1024x5120)
    float*          G     = (float*)(ws + 49 * MB);           // 256 KB
    __hip_bfloat16* Y1    = (__hip_bfloat16*)ws;              // reuse x region
    __hip_bfloat16* Y2    = QK;                               // reuse after attention

    const dim3 blk(256);
    conv_all_kernel<<<dim3((N_TOT / 4 + 255) / 256), blk, 0, stream>>>(
        d_in[0], d_in[1], d_in[2], d_in[3], d_in[4], d_in[5], d_in[6],
        d_in[7], d_in[8], d_in[9], d_in[10], arena);

    const __hip_bfloat16* xB  = arena + OFF_X;
    const __hip_bfloat16* WqB = arena + OFF_WQ;  // [Wq;Wk] contiguous
    const __hip_bfloat16* WvB = arena + OFF_WV;
    const __hip_bfloat16* WoB = arena + OFF_WO;

    qkv_kernel<<<dim3(960), blk, 0, stream>>>(xB, WqB, WvB, QK, Vt);
    gate_kernel<<<dim3(256), dim3(64), 0, stream>>>(QK, arena + OFF_GW, arena + OFF_GB, G);
    attn_kernel<<<dim3(1024), blk, 0, stream>>>(QK, Vt, G, Y1);
    canon_kernel<<<dim3(4096), blk, 0, stream>>>(Y1, arena + OFF_CW, arena + OFF_CB, Y2);
    gemm_bt_kernel<<<dim3(32, 8), blk, 0, stream>>>(Y2, WoB, d_out, 1024, 1);
}